// Round 1
// baseline (274.611 us; speedup 1.0000x reference)
//
#include <hip/hip_runtime.h>
#include <hip/hip_bf16.h>
#include <cstddef>

#define NH 16
#define HD 128

using short4_t = __attribute__((ext_vector_type(4))) short;
using short8_t = __attribute__((ext_vector_type(8))) short;
using f32x4    = __attribute__((ext_vector_type(4))) float;

__device__ __forceinline__ short f2bf(float f) {
    union { float f; unsigned u; } x; x.f = f;
    unsigned r = x.u + 0x7FFFu + ((x.u >> 16) & 1u);
    return (short)(r >> 16);
}

// One wave (64 threads) per block. Each wave owns 32 q-rows (2 subtiles of 16)
// of one head, and streams KV tiles of 16 rows with online softmax.
//
// Fragment plan (all verified against guide layouts):
//  QK^T swapped:  S^T = mfma_f32_16x16x32_bf16(A=K_tile, B=Q^T)
//    A-frag / B-frag: lane holds row (lane&15), d-offset (lane>>4)*8, 8 contiguous
//    D: lane holds S[q = lane&15][kv = (lane>>4)*4 + j]   (j=0..3)
//  PV swapped:    O^T = mfma_f32_16x16x16bf16_1k(A=V^T chunk, B=P^T)
//    A-frag: lane j-elem = V[kt*16 + (lane>>4)*4 + j][c2*16 + (lane&15)]
//    B-frag: lane j-elem = P[q = lane&15][kv = (lane>>4)*4 + j]  (= softmax output, in place)
//    D: lane holds O[q = lane&15][d = c2*16 + (lane>>4)*4 + j]  -> float4 stores
__global__ __launch_bounds__(64) void varlen_attn(
    const float* __restrict__ Q, const float* __restrict__ K,
    const float* __restrict__ V, const int* __restrict__ cu,
    int n_cu, int L, float* __restrict__ O)
{
    const int qt   = blockIdx.x;       // 32-row q block
    const int h    = blockIdx.y;       // head
    const int lane = threadIdx.x & 63;
    const int lo   = lane & 15;
    const int hi   = lane >> 4;

    int q_row[2];
    q_row[0] = qt * 32 + lo;
    q_row[1] = qt * 32 + 16 + lo;

    // per-row segment start (largest cu[i] <= q_row); cu[0]==0
    int seg_start[2];
    for (int m = 0; m < 2; ++m) {
        int ss = 0;
        for (int i = 1; i < n_cu; ++i) { int c = cu[i]; if (c <= q_row[m]) ss = c; else break; }
        seg_start[m] = ss;
    }
    int ss0 = 0;
    { int q0 = qt * 32; for (int i = 1; i < n_cu; ++i) { int c = cu[i]; if (c <= q0) ss0 = c; else break; } }

    const float scale = 0.08838834764831845f; // 1/sqrt(128)

    // Q fragments: qf[m][c], lane reads Q[q_row[m]][c*32 + hi*8 .. +7]
    short8_t qf[2][4];
    for (int m = 0; m < 2; ++m) {
        const float* qp = Q + ((size_t)q_row[m] * NH + h) * HD + hi * 8;
        #pragma unroll
        for (int c = 0; c < 4; ++c) {
            float4 a = *(const float4*)(qp + c * 32);
            float4 b = *(const float4*)(qp + c * 32 + 4);
            short8_t s;
            s[0] = f2bf(a.x); s[1] = f2bf(a.y); s[2] = f2bf(a.z); s[3] = f2bf(a.w);
            s[4] = f2bf(b.x); s[5] = f2bf(b.y); s[6] = f2bf(b.z); s[7] = f2bf(b.w);
            qf[m][c] = s;
        }
    }

    f32x4 o[2][8];
    #pragma unroll
    for (int m = 0; m < 2; ++m)
        #pragma unroll
        for (int c = 0; c < 8; ++c) { o[m][c][0] = 0.f; o[m][c][1] = 0.f; o[m][c][2] = 0.f; o[m][c][3] = 0.f; }
    float mrow[2] = {-1e30f, -1e30f};
    float lrow[2] = {0.f, 0.f};

    const int kt0 = ss0 >> 4;
    const int kt1 = (qt * 32 + 31) >> 4;

    for (int kt = kt0; kt <= kt1; ++kt) {
        // K fragments (shared by both q subtiles)
        short8_t kf[4];
        {
            const float* kp = K + ((size_t)(kt * 16 + lo) * NH + h) * HD + hi * 8;
            #pragma unroll
            for (int c = 0; c < 4; ++c) {
                float4 a = *(const float4*)(kp + c * 32);
                float4 b = *(const float4*)(kp + c * 32 + 4);
                short8_t s;
                s[0] = f2bf(a.x); s[1] = f2bf(a.y); s[2] = f2bf(a.z); s[3] = f2bf(a.w);
                s[4] = f2bf(b.x); s[5] = f2bf(b.y); s[6] = f2bf(b.z); s[7] = f2bf(b.w);
                kf[c] = s;
            }
        }
        // V fragments: vf[c2][j] = V[kt*16 + hi*4 + j][c2*16 + lo]
        short4_t vf[8];
        {
            const float* vp = V + ((size_t)(kt * 16 + hi * 4) * NH + h) * HD + lo;
            #pragma unroll
            for (int c2 = 0; c2 < 8; ++c2) {
                short4_t s;
                #pragma unroll
                for (int j = 0; j < 4; ++j)
                    s[j] = f2bf(vp[(size_t)j * (NH * HD) + c2 * 16]);
                vf[c2] = s;
            }
        }

        #pragma unroll
        for (int m = 0; m < 2; ++m) {
            // S^T tile
            f32x4 sacc; sacc[0] = 0.f; sacc[1] = 0.f; sacc[2] = 0.f; sacc[3] = 0.f;
            #pragma unroll
            for (int c = 0; c < 4; ++c)
                sacc = __builtin_amdgcn_mfma_f32_16x16x32_bf16(kf[c], qf[m][c], sacc, 0, 0, 0);

            // masked tile max over this lane's 4 scores, then row-reduce
            float tm = -1e30f;
            bool validj[4];
            #pragma unroll
            for (int j = 0; j < 4; ++j) {
                int kidx = kt * 16 + hi * 4 + j;
                validj[j] = (kidx >= seg_start[m]) && (kidx <= q_row[m]);
                float sc = sacc[j] * scale;
                sacc[j] = sc;
                if (validj[j]) tm = fmaxf(tm, sc);
            }
            tm = fmaxf(tm, __shfl_xor(tm, 16));
            tm = fmaxf(tm, __shfl_xor(tm, 32));

            float mnew = fmaxf(mrow[m], tm);
            float sold = __expf(mrow[m] - mnew);   // ==1 when both -1e30 (o,l still 0: harmless)

            float ps = 0.f;
            short4_t pf;
            #pragma unroll
            for (int j = 0; j < 4; ++j) {
                float pj = validj[j] ? __expf(sacc[j] - mnew) : 0.f;
                ps += pj;
                pf[j] = f2bf(pj);
            }
            ps += __shfl_xor(ps, 16);
            ps += __shfl_xor(ps, 32);
            lrow[m] = lrow[m] * sold + ps;
            mrow[m] = mnew;

            #pragma unroll
            for (int c2 = 0; c2 < 8; ++c2) {
                f32x4 t = o[m][c2];
                t[0] *= sold; t[1] *= sold; t[2] *= sold; t[3] *= sold;
                o[m][c2] = __builtin_amdgcn_mfma_f32_16x16x16bf16_1k(vf[c2], pf, t, 0, 0, 0);
            }
        }
    }

    // epilogue: O[q_row[m]][c2*16 + hi*4 + j] , j contiguous -> float4
    #pragma unroll
    for (int m = 0; m < 2; ++m) {
        float inv = 1.0f / lrow[m];
        float* op = O + ((size_t)q_row[m] * NH + h) * HD + hi * 4;
        #pragma unroll
        for (int c2 = 0; c2 < 8; ++c2) {
            f32x4 t = o[m][c2];
            float4 w;
            w.x = t[0] * inv; w.y = t[1] * inv; w.z = t[2] * inv; w.w = t[3] * inv;
            *(float4*)(op + c2 * 16) = w;
        }
    }
}

extern "C" void kernel_launch(void* const* d_in, const int* in_sizes, int n_in,
                              void* d_out, int out_size, void* d_ws, size_t ws_size,
                              hipStream_t stream) {
    const float* Q = (const float*)d_in[0];
    const float* K = (const float*)d_in[1];
    const float* V = (const float*)d_in[2];
    const int* cu  = (const int*)d_in[3];
    int n_cu = in_sizes[3];
    int L = in_sizes[0] / (NH * HD);

    dim3 grid(L / 32, NH);
    varlen_attn<<<grid, 64, 0, stream>>>(Q, K, V, cu, n_cu, L, (float*)d_out);
}

// Round 2
// 192.192 us; speedup vs baseline: 1.4288x; 1.4288x over previous
//
#include <hip/hip_runtime.h>
#include <hip/hip_bf16.h>
#include <cstddef>

#define NH 16
#define HD 128
#define NW 4   // waves per block, splitting KV

using short4_t = __attribute__((ext_vector_type(4))) short;
using short8_t = __attribute__((ext_vector_type(8))) short;
using f32x4    = __attribute__((ext_vector_type(4))) float;

__device__ __forceinline__ short f2bf(float f) {
    union { float f; unsigned u; } x; x.f = f;
    unsigned r = x.u + 0x7FFFu + ((x.u >> 16) & 1u);
    return (short)(r >> 16);
}

// 4 waves per block. All waves own the SAME 32 q-rows of one head; KV tiles
// (16 rows) are strided across waves (kt = kt0 + w + 4*i). Each wave keeps a
// private online-softmax state (m, l, o); the epilogue combines the 4 partials
// flash-decode style via LDS:
//   M = max_w m_w ; L = sum_w l_w * exp(m_w - M) ; O = sum_w o_w*exp(m_w-M) / L
//
// Fragment plan per wave (identical to round 1):
//  QK^T swapped:  S^T = mfma_f32_16x16x32_bf16(A=K_tile, B=Q^T)
//    D: lane holds S[q = lane&15][kv = (lane>>4)*4 + j]
//  PV swapped:    O^T = mfma_f32_16x16x16bf16_1k(A=V^T chunk, B=P^T)
//    D: lane holds O[q = lane&15][d = c2*16 + (lane>>4)*4 + j]
__global__ __launch_bounds__(256) void varlen_attn(
    const float* __restrict__ Q, const float* __restrict__ K,
    const float* __restrict__ V, const int* __restrict__ cu,
    int n_cu, int L, float* __restrict__ O)
{
    __shared__ float Osum[32][132];   // +4 pad: float4 ops land 2-way max
    __shared__ float Mw[NW][32];
    __shared__ float Lw[NW][32];
    __shared__ float Linv[32];

    const int qt   = blockIdx.x;       // 32-row q block
    const int h    = blockIdx.y;       // head
    const int tid  = threadIdx.x;
    const int w    = tid >> 6;
    const int lane = tid & 63;
    const int lo   = lane & 15;
    const int hi   = lane >> 4;

    int q_row[2];
    q_row[0] = qt * 32 + lo;
    q_row[1] = qt * 32 + 16 + lo;

    int seg_start[2];
    #pragma unroll
    for (int m = 0; m < 2; ++m) {
        int ss = 0;
        for (int i = 1; i < n_cu; ++i) { int c = cu[i]; if (c <= q_row[m]) ss = c; else break; }
        seg_start[m] = ss;
    }
    int ss0 = 0;
    { int q0 = qt * 32; for (int i = 1; i < n_cu; ++i) { int c = cu[i]; if (c <= q0) ss0 = c; else break; } }

    const float scale = 0.08838834764831845f; // 1/sqrt(128)

    // Q fragments: qf[m][c], lane reads Q[q_row[m]][c*32 + hi*8 .. +7]
    short8_t qf[2][4];
    #pragma unroll
    for (int m = 0; m < 2; ++m) {
        const float* qp = Q + ((size_t)q_row[m] * NH + h) * HD + hi * 8;
        #pragma unroll
        for (int c = 0; c < 4; ++c) {
            float4 a = *(const float4*)(qp + c * 32);
            float4 b = *(const float4*)(qp + c * 32 + 4);
            short8_t s;
            s[0] = f2bf(a.x); s[1] = f2bf(a.y); s[2] = f2bf(a.z); s[3] = f2bf(a.w);
            s[4] = f2bf(b.x); s[5] = f2bf(b.y); s[6] = f2bf(b.z); s[7] = f2bf(b.w);
            qf[m][c] = s;
        }
    }

    f32x4 o[2][8];
    #pragma unroll
    for (int m = 0; m < 2; ++m)
        #pragma unroll
        for (int c = 0; c < 8; ++c) { o[m][c][0] = 0.f; o[m][c][1] = 0.f; o[m][c][2] = 0.f; o[m][c][3] = 0.f; }
    float mrow[2] = {-1e30f, -1e30f};
    float lrow[2] = {0.f, 0.f};

    const int kt0 = ss0 >> 4;
    const int kt1 = (qt * 32 + 31) >> 4;

    for (int kt = kt0 + w; kt <= kt1; kt += NW) {
        short8_t kf[4];
        {
            const float* kp = K + ((size_t)(kt * 16 + lo) * NH + h) * HD + hi * 8;
            #pragma unroll
            for (int c = 0; c < 4; ++c) {
                float4 a = *(const float4*)(kp + c * 32);
                float4 b = *(const float4*)(kp + c * 32 + 4);
                short8_t s;
                s[0] = f2bf(a.x); s[1] = f2bf(a.y); s[2] = f2bf(a.z); s[3] = f2bf(a.w);
                s[4] = f2bf(b.x); s[5] = f2bf(b.y); s[6] = f2bf(b.z); s[7] = f2bf(b.w);
                kf[c] = s;
            }
        }
        // V fragments: vf[c2][j] = V[kt*16 + hi*4 + j][c2*16 + lo]
        short4_t vf[8];
        {
            const float* vp = V + ((size_t)(kt * 16 + hi * 4) * NH + h) * HD + lo;
            #pragma unroll
            for (int c2 = 0; c2 < 8; ++c2) {
                short4_t s;
                #pragma unroll
                for (int j = 0; j < 4; ++j)
                    s[j] = f2bf(vp[(size_t)j * (NH * HD) + c2 * 16]);
                vf[c2] = s;
            }
        }

        #pragma unroll
        for (int m = 0; m < 2; ++m) {
            f32x4 sacc; sacc[0] = 0.f; sacc[1] = 0.f; sacc[2] = 0.f; sacc[3] = 0.f;
            #pragma unroll
            for (int c = 0; c < 4; ++c)
                sacc = __builtin_amdgcn_mfma_f32_16x16x32_bf16(kf[c], qf[m][c], sacc, 0, 0, 0);

            float tm = -1e30f;
            bool validj[4];
            #pragma unroll
            for (int j = 0; j < 4; ++j) {
                int kidx = kt * 16 + hi * 4 + j;
                validj[j] = (kidx >= seg_start[m]) && (kidx <= q_row[m]);
                float sc = sacc[j] * scale;
                sacc[j] = sc;
                if (validj[j]) tm = fmaxf(tm, sc);
            }
            tm = fmaxf(tm, __shfl_xor(tm, 16));
            tm = fmaxf(tm, __shfl_xor(tm, 32));

            float mnew = fmaxf(mrow[m], tm);
            float sold = __expf(mrow[m] - mnew);

            float ps = 0.f;
            short4_t pf;
            #pragma unroll
            for (int j = 0; j < 4; ++j) {
                float pj = validj[j] ? __expf(sacc[j] - mnew) : 0.f;
                ps += pj;
                pf[j] = f2bf(pj);
            }
            ps += __shfl_xor(ps, 16);
            ps += __shfl_xor(ps, 32);
            lrow[m] = lrow[m] * sold + ps;
            mrow[m] = mnew;

            #pragma unroll
            for (int c2 = 0; c2 < 8; ++c2) {
                f32x4 t = o[m][c2];
                t[0] *= sold; t[1] *= sold; t[2] *= sold; t[3] *= sold;
                o[m][c2] = __builtin_amdgcn_mfma_f32_16x16x16bf16_1k(vf[c2], pf, t, 0, 0, 0);
            }
        }
    }

    // ---- combine the 4 partial (m,l,o) states ----
    if (hi == 0) {
        #pragma unroll
        for (int m = 0; m < 2; ++m) { Mw[w][m * 16 + lo] = mrow[m]; Lw[w][m * 16 + lo] = lrow[m]; }
    }
    __syncthreads();

    float sc2[2];
    #pragma unroll
    for (int m = 0; m < 2; ++m) {
        int r = m * 16 + lo;
        float M = Mw[0][r];
        #pragma unroll
        for (int ww = 1; ww < NW; ++ww) M = fmaxf(M, Mw[ww][r]);
        float Lt = 0.f;
        #pragma unroll
        for (int ww = 0; ww < NW; ++ww) Lt += Lw[ww][r] * __expf(Mw[ww][r] - M);
        sc2[m] = __expf(mrow[m] - M);
        if (w == 0 && hi == 0) Linv[r] = 1.0f / Lt;
    }

    // turn-based accumulation of o_w * sc into Osum
    #pragma unroll
    for (int t = 0; t < NW; ++t) {
        __syncthreads();
        if (w == t) {
            #pragma unroll
            for (int m = 0; m < 2; ++m) {
                #pragma unroll
                for (int c2 = 0; c2 < 8; ++c2) {
                    float4* dst = (float4*)&Osum[m * 16 + lo][c2 * 16 + hi * 4];
                    f32x4 v = o[m][c2];
                    float4 val;
                    val.x = v[0] * sc2[m]; val.y = v[1] * sc2[m];
                    val.z = v[2] * sc2[m]; val.w = v[3] * sc2[m];
                    if (t == 0) { *dst = val; }
                    else { float4 prev = *dst; prev.x += val.x; prev.y += val.y; prev.z += val.z; prev.w += val.w; *dst = prev; }
                }
            }
        }
    }
    __syncthreads();

    // coalesced output: 1024 float4 chunks over 256 threads
    #pragma unroll
    for (int k = 0; k < 4; ++k) {
        int idx = k * 256 + tid;
        int r   = idx >> 5;        // 0..31
        int c4  = idx & 31;        // float4 index within row
        float4 v = *(const float4*)&Osum[r][c4 * 4];
        float li = Linv[r];
        v.x *= li; v.y *= li; v.z *= li; v.w *= li;
        *(float4*)(O + ((size_t)(qt * 32 + r) * NH + h) * HD + c4 * 4) = v;
    }
}

extern "C" void kernel_launch(void* const* d_in, const int* in_sizes, int n_in,
                              void* d_out, int out_size, void* d_ws, size_t ws_size,
                              hipStream_t stream) {
    const float* Q = (const float*)d_in[0];
    const float* K = (const float*)d_in[1];
    const float* V = (const float*)d_in[2];
    const int* cu  = (const int*)d_in[3];
    int n_cu = in_sizes[3];
    int L = in_sizes[0] / (NH * HD);

    dim3 grid(L / 32, NH);
    varlen_attn<<<grid, 256, 0, stream>>>(Q, K, V, cu, n_cu, L, (float*)d_out);
}